// Round 23
// baseline (169.528 us; speedup 1.0000x reference)
//
#include <hip/hip_runtime.h>

#define B_    32
#define N_    256
#define H_    6
#define HD_   32
#define C_    192
#define C4_   768
#define TKIN  64
#define TKOUT 32

// ---------------------------------------------------------------------------
// Kernel A: one wave per (b,h,i) row; lane t owns sparse key slot t.
// Bit-identical arithmetic to R22-PASS (f32 canonical chain, shuffle pairwise
// sums, okey=exp(acc64)*pv, tie-aware comparator). Data movement rebuilt:
//  - rank loop: __shfl with unrolled-constant j -> v_readlane (no LDS)
//  - compaction: ds_permute push to lane=rank -> top-32 in lanes 0..31,
//    coalesced stores
//  - PV: ds_bpermute pulls (av,vi) per slot
//  - ZERO __shared__ usage.
// ---------------------------------------------------------------------------
__global__ __launch_bounds__(256) void attn_topk_kernel(
    const float* __restrict__ qkvp,
    const float* __restrict__ pfa_values,
    const int*   __restrict__ pfa_index,
    const int*   __restrict__ rpi,
    const float* __restrict__ rpb_table,
    float* __restrict__ x_pre,
    float* __restrict__ out_topv,
    float* __restrict__ out_nidx)
{
    const int lane  = threadIdx.x & 63;
    const int wslot = threadIdx.x >> 6;
    const int row   = (blockIdx.x << 2) + wslot;
    const int b   = row / (H_ * N_);
    const int rem = row - b * (H_ * N_);
    const int h   = rem / N_;
    const int i   = rem - h * N_;

    const int row_off = row * TKIN;
    const int idx  = pfa_index[row_off + lane];
    const float pv = pfa_values[row_off + lane];

    const float* qp = qkvp + (size_t)(b * N_ + i) * C4_ + h * HD_;
    const float* kp = qkvp + (size_t)(b * N_ + idx) * C4_ + C_ + h * HD_;
    const float bias = rpb_table[rpi[i * N_ + idx] * H_ + h];

    // ---- vector-load q,k into registers ----
    float4 qv[8], kv[8];
    #pragma unroll
    for (int d0 = 0; d0 < 8; ++d0) {
        qv[d0] = *(const float4*)(qp + 4 * d0);
        kv[d0] = *(const float4*)(kp + 4 * d0);
    }

    // ---- f32 chain: sequential no-FMA dot (bit-exact) ----
    float acc;
    {
        #pragma clang fp contract(off)
        const float SC = 0.17677669529663687f;
        acc = 0.f;
        #pragma unroll
        for (int d0 = 0; d0 < 8; ++d0) {
            const float* q4 = (const float*)&qv[d0];
            const float* k4 = (const float*)&kv[d0];
            #pragma unroll
            for (int t = 0; t < 4; ++t) {
                const float qd   = q4[t] * SC;
                const float prod = qd * k4[t];
                acc = acc + prod;
            }
        }
        acc = acc + bias;
    }
    // ---- f64 order key (same arithmetic as R22-PASS) ----
    double acc64;
    {
        const double SCD = 0.17677669529663687;
        acc64 = 0.0;
        #pragma unroll
        for (int d0 = 0; d0 < 8; ++d0) {
            const float* q4 = (const float*)&qv[d0];
            const float* k4 = (const float*)&kv[d0];
            #pragma unroll
            for (int t = 0; t < 4; ++t)
                acc64 += ((double)q4[t] * SCD) * (double)k4[t];
        }
        acc64 += (double)bias;
    }
    const double okey = exp(acc64) * (double)pv;

    // ---- f32 row max (exact, order-independent) ----
    float m = acc;
    #pragma unroll
    for (int s = 32; s; s >>= 1) m = fmaxf(m, __shfl_xor(m, s));

    // ---- e = exp(acc - m), correctly-rounded f32 via double ----
    float e;
    {
        #pragma clang fp contract(off)
        const float t = acc - m;
        e = (float)exp((double)t);
    }

    // ---- ssum: numpy pairwise-8 via shuffles (bit-exact, R22) ----
    float ssum;
    {
        #pragma clang fp contract(off)
        float y = e, r = e;
        #pragma unroll
        for (int k = 1; k < 8; ++k) { y = __shfl_down(y, 8); r = r + y; }
        const float t1 = r  + __shfl_xor(r, 1);
        const float t2 = t1 + __shfl_xor(t1, 2);
        const float t3 = t2 + __shfl_xor(t2, 4);
        ssum = __shfl(t3, 0);
    }

    // ---- w = (e/ssum)*pv ----
    float w;
    {
        #pragma clang fp contract(off)
        const float s32 = e / ssum;
        w = s32 * pv;
    }

    // ---- denom: same shuffle pairwise-8 over w ----
    float denom;
    {
        #pragma clang fp contract(off)
        float y = w, r = w;
        #pragma unroll
        for (int k = 1; k < 8; ++k) { y = __shfl_down(y, 8); r = r + y; }
        const float t1 = r  + __shfl_xor(r, 1);
        const float t2 = t1 + __shfl_xor(t1, 2);
        const float t3 = t2 + __shfl_xor(t2, 4);
        denom = __shfl(t3, 0);
    }

    // ---- a32 = (w + EPS)/(denom + EPS) ----
    float a32;
    {
        #pragma clang fp contract(off)
        a32 = (w + 1e-20f) / (denom + 1e-20f);
    }

    // ---- rank: readlane broadcasts (unrolled j => v_readlane) ----
    int rank = 0;
    #pragma unroll
    for (int j = 0; j < 64; ++j) {
        const float  kj32 = __shfl(a32, j);
        const double kj64 = __shfl(okey, j);
        bool before;
        if (kj32 == a32) {
            before = (kj64 < okey) || (kj64 == okey && j < lane);
        } else {
            before = (kj64 > okey) ||
                     (kj64 == okey && (kj32 > a32 || (kj32 == a32 && j < lane)));
        }
        rank += before;
    }

    // ---- compaction: push (a32, idx) to lane == rank ----
    const int pa = __builtin_amdgcn_ds_permute(rank << 2, __float_as_int(a32));
    const int pi = __builtin_amdgcn_ds_permute(rank << 2, idx);
    const float paf = __int_as_float(pa);

    if (lane < TKOUT) {
        const size_t obase = (size_t)row * TKOUT + lane;
        out_topv[obase] = paf;
        out_nidx[obase] = (float)pi;
    }

    // ---- PV: lanes (d, half); slot values pulled via bpermute ----
    const int d    = lane & 31;
    const int half = lane >> 5;
    float xd = 0.f;
    #pragma unroll
    for (int s16 = 0; s16 < 16; ++s16) {
        const int sI = half * 16 + s16;
        const float av = __shfl(paf, sI);
        const int   vi = __shfl(pi, sI);
        xd += av * qkvp[(size_t)(b * N_ + vi) * C4_ + 2 * C_ + h * HD_ + d];
    }
    xd += __shfl_xor(xd, 32);
    if (half == 0) {
        const float lepe = qkvp[(size_t)(b * N_ + i) * C4_ + 3 * C_ + h * HD_ + d];
        x_pre[(size_t)(b * N_ + i) * C_ + h * HD_ + d] = xd + lepe;
    }
}

// ---------------------------------------------------------------------------
#define TB_ 8
__global__ __launch_bounds__(192) void proj_kernel(
    const float* __restrict__ x_pre,
    const float* __restrict__ w,
    const float* __restrict__ bias,
    float* __restrict__ out)
{
    __shared__ float xs[TB_ * C_];
    const int o    = threadIdx.x;
    const int tok0 = blockIdx.x * TB_;

    #pragma unroll
    for (int r = 0; r < TB_; ++r)
        xs[r * C_ + o] = x_pre[(size_t)(tok0 + r) * C_ + o];
    __syncthreads();

    float accv[TB_];
    #pragma unroll
    for (int t = 0; t < TB_; ++t) accv[t] = 0.f;

    const float* wrow = w + (size_t)o * C_;
    for (int c = 0; c < C_; c += 4) {
        const float4 wv = *(const float4*)(wrow + c);
        #pragma unroll
        for (int t = 0; t < TB_; ++t) {
            const float4 xv = *(const float4*)(&xs[t * C_ + c]);
            accv[t] += xv.x * wv.x + xv.y * wv.y + xv.z * wv.z + xv.w * wv.w;
        }
    }
    const float bo = bias[o];
    #pragma unroll
    for (int t = 0; t < TB_; ++t)
        out[(size_t)(tok0 + t) * C_ + o] = accv[t] + bo;
}

// ---------------------------------------------------------------------------
extern "C" void kernel_launch(void* const* d_in, const int* in_sizes, int n_in,
                              void* d_out, int out_size, void* d_ws, size_t ws_size,
                              hipStream_t stream) {
    const float* qkvp       = (const float*)d_in[0];
    const float* pfa_values = (const float*)d_in[1];
    const int*   pfa_index  = (const int*)d_in[2];
    const int*   rpi        = (const int*)d_in[3];
    const float* rpb_table  = (const float*)d_in[4];
    const float* proj_w     = (const float*)d_in[5];
    const float* proj_b     = (const float*)d_in[6];

    float* out = (float*)d_out;
    float* out_x    = out;
    float* out_topv = out + (size_t)B_ * N_ * C_;
    float* out_nidx = out_topv + (size_t)B_ * H_ * N_ * TKOUT;

    float* x_pre = (float*)d_ws;

    const int rows = B_ * H_ * N_;
    attn_topk_kernel<<<rows / 4, 256, 0, stream>>>(
        qkvp, pfa_values, pfa_index, rpi, rpb_table, x_pre, out_topv, out_nidx);

    const int ntok = B_ * N_;
    proj_kernel<<<ntok / TB_, 192, 0, stream>>>(x_pre, proj_w, proj_b, out_x);
}